// Round 5
// baseline (2986.326 us; speedup 1.0000x reference)
//
#include <hip/hip_runtime.h>
#include <float.h>

#define N4K 4096
#define NP1 4097

typedef __attribute__((ext_vector_type(4))) float f32x4;
typedef __attribute__((ext_vector_type(8))) short bf16x8;

__device__ __forceinline__ unsigned short f2bf(float x) {
    union { float f; unsigned int u; } v; v.f = x;
    unsigned int r = v.u + 0x7FFFu + ((v.u >> 16) & 1u);   // round-nearest-even
    return (unsigned short)(r >> 16);
}

__device__ __forceinline__ void gload_lds16(const void* g, void* l) {
    __builtin_amdgcn_global_load_lds(
        (const __attribute__((address_space(1))) unsigned int*)g,
        (__attribute__((address_space(3))) unsigned int*)l,
        16, 0, 0);
}

__device__ __forceinline__ void bar() {
    asm volatile("" ::: "memory");
    __builtin_amdgcn_s_barrier();
    asm volatile("" ::: "memory");
}

// ---- prep: W2 row -> bf16 cast + fused bias-matvec
__global__ __launch_bounds__(256) void prep_A2(const float* __restrict__ W2lb,
                                               const float* __restrict__ W2ub,
                                               const float* __restrict__ mb,
                                               const float* __restrict__ db,
                                               unsigned short* __restrict__ Abf,
                                               float* __restrict__ bias_part) {
    int b = blockIdx.x;                 // 0..8191
    int chain = b >> 12, i = b & 4095;
    const float* row = (chain ? W2ub : W2lb) + (long long)i * NP1;
    unsigned short* abf_row = Abf + ((long long)chain << 24) + (long long)i * N4K;
    float s = chain ? 1.f : -1.f;
    float part = 0.f;
#pragma unroll 4
    for (int p = 0; p < 16; ++p) {
        int k = threadIdx.x + p * 256;
        float wv = row[k];
        abf_row[k] = f2bf(wv);
        part += wv * mb[k] + s * db[k] * fabsf(wv);
    }
    __shared__ float red[4];
#pragma unroll
    for (int off = 32; off; off >>= 1) part += __shfl_down(part, off);
    if ((threadIdx.x & 63) == 0) red[threadIdx.x >> 6] = part;
    __syncthreads();
    if (threadIdx.x == 0)
        bias_part[b] = red[0] + red[1] + red[2] + red[3] + row[4096];
}

// ---- prep: build M^T, D^T bf16 [4096 j][4096 k] via LDS tile transpose
__global__ __launch_bounds__(256) void prep_B(const float* __restrict__ W1lb,
                                              const float* __restrict__ W1ub,
                                              unsigned short* __restrict__ Bmt,
                                              unsigned short* __restrict__ Bdt) {
    __shared__ unsigned short Lm[64 * 65];
    __shared__ unsigned short Ld[64 * 65];
    int j0 = blockIdx.x * 64, k0 = blockIdx.y * 64;
    int t = threadIdx.x;
    int jj = t & 63, kkb = t >> 6;
#pragma unroll 4
    for (int p = 0; p < 16; ++p) {
        int kk = kkb + p * 4;
        long long off = (long long)(k0 + kk) * NP1 + j0 + jj;
        float l = W1lb[off], u = W1ub[off];
        Lm[kk * 65 + jj] = f2bf(0.5f * (l + u));
        Ld[kk * 65 + jj] = f2bf(0.5f * (u - l));
    }
    __syncthreads();
#pragma unroll
    for (int p = 0; p < 2; ++p) {
        int jl = p * 32 + (t >> 3);
        int kl = (t & 7) * 8;
        bf16x8 vm, vd;
#pragma unroll
        for (int i = 0; i < 8; ++i) {
            vm[i] = (short)Lm[(kl + i) * 65 + jl];
            vd[i] = (short)Ld[(kl + i) * 65 + jl];
        }
        *(bf16x8*)&Bmt[(long long)(j0 + jl) * N4K + k0 + kl] = vm;
        *(bf16x8*)&Bdt[(long long)(j0 + jl) * N4K + k0 + kl] = vd;
    }
}

// ---- prep: bias column of W1 -> mb, db (fp32)
__global__ __launch_bounds__(256) void prep_mbdb(const float* __restrict__ W1lb,
                                                 const float* __restrict__ W1ub,
                                                 float* __restrict__ mb,
                                                 float* __restrict__ db) {
    int k = blockIdx.x * 256 + threadIdx.x;
    if (k < N4K) {
        float l = W1lb[(long long)k * NP1 + 4096];
        float u = W1ub[(long long)k * NP1 + 4096];
        mb[k] = 0.5f * (l + u);
        db[k] = 0.5f * (u - l);
    }
}

// ---- fused GEMM: 256x256 tile, BK=32, ring-3 LDS, 1 barrier/K-tile, counted vmcnt(6)
__global__ __launch_bounds__(512, 2) void gemm_fused(const unsigned short* __restrict__ Abf,
                                                     const unsigned short* __restrict__ Bmt,
                                                     const unsigned short* __restrict__ Bdt,
                                                     const float* __restrict__ lb0,
                                                     const float* __restrict__ ub0,
                                                     float* __restrict__ pp) {
    __shared__ unsigned short As[3][8192];    // 256 rows x 32 k
    __shared__ unsigned short Bms[3][8192];   // 256 cols x 32 k
    __shared__ unsigned short Bds[3][8192];

    int wg = blockIdx.x;
    int swz = (wg & 7) * 64 + (wg >> 3);      // XCD-aware bijective (512 % 8 == 0)
    int rt = swz & 31;                        // row tile: 16 lb + 16 ub
    int ct = swz >> 5;                        // col tile 0..15

    int chain = rt >> 4;
    const unsigned short* Aptr = Abf + ((long long)chain << 24) + (long long)(rt & 15) * 256 * N4K;
    const unsigned short* Bmp = Bmt + (long long)ct * 256 * N4K;
    const unsigned short* Bdp = Bdt + (long long)ct * 256 * N4K;

    int tid = threadIdx.x;
    int lane = tid & 63, w = tid >> 6;
    int wr = w >> 2, wc = w & 3;              // 2M x 4N waves, 128x64 per wave
    int la = lane & 15, kq = lane >> 4;
    int cA = (kq ^ ((la >> 1) & 3)) * 8;      // swizzled chunk offset (shorts)

    // staging source map (inverse-swizzled global chunk; linear LDS dest)
    int sr = tid >> 2;                               // 0..127
    int sce = ((tid & 3) ^ ((tid >> 3) & 3)) << 3;   // chunk*8 shorts
    const unsigned short* aB = Aptr + (long long)sr * N4K + sce;
    const unsigned short* mB = Bmp + (long long)sr * N4K + sce;
    const unsigned short* dB = Bdp + (long long)sr * N4K + sce;
    const long long R128 = 128LL * N4K;
    unsigned w512 = w * 512;                         // wave-uniform LDS base (shorts)

    int arow = wr * 128 + la;
    int brow = wc * 64 + la;

    f32x4 acc[8][4];
#pragma unroll
    for (int m = 0; m < 8; ++m)
#pragma unroll
        for (int n = 0; n < 4; ++n) acc[m][n] = (f32x4){0.f, 0.f, 0.f, 0.f};

#define STAGE(slot, koff)                                              \
    do {                                                               \
        gload_lds16(aB + (koff), &As[slot][w512]);                     \
        gload_lds16(aB + R128 + (koff), &As[slot][4096 + w512]);       \
        gload_lds16(mB + (koff), &Bms[slot][w512]);                    \
        gload_lds16(mB + R128 + (koff), &Bms[slot][4096 + w512]);      \
        gload_lds16(dB + (koff), &Bds[slot][w512]);                    \
        gload_lds16(dB + R128 + (koff), &Bds[slot][4096 + w512]);      \
    } while (0)

    // prologue: stage tiles 0,1 ; wait tile 0 ; barrier
    STAGE(0, 0);
    STAGE(1, 32);
    asm volatile("s_waitcnt vmcnt(6)" ::: "memory");
    bar();

#define FRAG(arr, s, rb) (*(const bf16x8*)&arr[s][((rb) + la) * 32 + cA])

    int cs = 0, st = 2;
#pragma unroll 1
    for (int t = 0; t < 128; ++t) {
        const bool pf = (t + 2 < 128);

        bf16x8 a[8], bm0[2], bd0[2], bm1[2], bd1[2];
#pragma unroll
        for (int m = 0; m < 8; ++m) a[m] = FRAG(As, cs, wr * 128 + m * 16);
        (void)arow;
#pragma unroll
        for (int n = 0; n < 2; ++n) {
            bm0[n] = FRAG(Bms, cs, wc * 64 + n * 16);
            bd0[n] = FRAG(Bds, cs, wc * 64 + n * 16);
        }
        if (pf) {
            long long koff = (long long)(t + 2) * 32;
            gload_lds16(aB + koff, &As[st][w512]);
            gload_lds16(aB + R128 + koff, &As[st][4096 + w512]);
            gload_lds16(mB + koff, &Bms[st][w512]);
        }
        __builtin_amdgcn_s_setprio(1);
#pragma unroll
        for (int m = 0; m < 8; ++m) {
            bf16x8 ax = chain ? (a[m] & (short)0x7FFF) : (a[m] | (short)0x8000);
#pragma unroll
            for (int n = 0; n < 2; ++n) {
                acc[m][n] = __builtin_amdgcn_mfma_f32_16x16x32_bf16(a[m], bm0[n], acc[m][n], 0, 0, 0);
                acc[m][n] = __builtin_amdgcn_mfma_f32_16x16x32_bf16(ax, bd0[n], acc[m][n], 0, 0, 0);
            }
        }
        __builtin_amdgcn_s_setprio(0);

#pragma unroll
        for (int n = 0; n < 2; ++n) {
            bm1[n] = FRAG(Bms, cs, wc * 64 + (n + 2) * 16);
            bd1[n] = FRAG(Bds, cs, wc * 64 + (n + 2) * 16);
        }
        if (pf) {
            long long koff = (long long)(t + 2) * 32;
            gload_lds16(mB + R128 + koff, &Bms[st][4096 + w512]);
            gload_lds16(dB + koff, &Bds[st][w512]);
            gload_lds16(dB + R128 + koff, &Bds[st][4096 + w512]);
        }
        __builtin_amdgcn_s_setprio(1);
#pragma unroll
        for (int m = 0; m < 8; ++m) {
            bf16x8 ax = chain ? (a[m] & (short)0x7FFF) : (a[m] | (short)0x8000);
#pragma unroll
            for (int n = 0; n < 2; ++n) {
                acc[m][n + 2] = __builtin_amdgcn_mfma_f32_16x16x32_bf16(a[m], bm1[n], acc[m][n + 2], 0, 0, 0);
                acc[m][n + 2] = __builtin_amdgcn_mfma_f32_16x16x32_bf16(ax, bd1[n], acc[m][n + 2], 0, 0, 0);
            }
        }
        __builtin_amdgcn_s_setprio(0);

        // boundary: require tile t+1 landed; leave tile t+2's 6 loads in flight
        if (pf) asm volatile("s_waitcnt vmcnt(6)" ::: "memory");
        else    asm volatile("s_waitcnt vmcnt(0)" ::: "memory");
        bar();

        cs = (cs == 2) ? 0 : cs + 1;
        st = (st == 2) ? 0 : st + 1;
    }
#undef FRAG
#undef STAGE

    // fused second backsub stage -> uncontended partial stores
    float s = chain ? 1.f : -1.f;
    float rowpart[8][4];
#pragma unroll
    for (int m = 0; m < 8; ++m)
#pragma unroll
        for (int r = 0; r < 4; ++r) rowpart[m][r] = 0.f;

    int jbase = ct * 256 + wc * 64;
#pragma unroll
    for (int n = 0; n < 4; ++n) {
        int j = jbase + n * 16 + la;
        float l0 = lb0[j], u0 = ub0[j];
        float mj = 0.5f * (l0 + u0);
        float sdj = s * 0.5f * (u0 - l0);
#pragma unroll
        for (int m = 0; m < 8; ++m)
#pragma unroll
            for (int r = 0; r < 4; ++r) {
                float v = acc[m][n][r];
                rowpart[m][r] += v * mj + sdj * fabsf(v);
            }
    }
    long long rowg = (long long)chain * N4K + (rt & 15) * 256 + wr * 128 + kq * 4;
    long long slice = (long long)(ct * 4 + wc) * 8192;
#pragma unroll
    for (int m = 0; m < 8; ++m)
#pragma unroll
        for (int r = 0; r < 4; ++r) {
            float v = rowpart[m][r];
            v += __shfl_xor(v, 1);
            v += __shfl_xor(v, 2);
            v += __shfl_xor(v, 4);
            v += __shfl_xor(v, 8);
            if (la == 0) pp[slice + rowg + m * 16 + r] = v;
        }
}

// ---- reduce 64 partial slices + bias -> prev[8192]
__global__ __launch_bounds__(256) void reduce_pp(const float* __restrict__ pp,
                                                 const float* __restrict__ bias_part,
                                                 float* __restrict__ prev) {
    int j = blockIdx.x * 256 + threadIdx.x;
    float s = bias_part[j];
#pragma unroll 8
    for (int c = 0; c < 64; ++c) s += pp[(long long)c * 8192 + j];
    prev[j] = s;
}

// ---- epilogue: PReLU relaxation, scatter diag + bias col
__global__ __launch_bounds__(256) void epilogue(const float* __restrict__ prev,
                                                const float* __restrict__ alphas,
                                                float* __restrict__ out) {
    int i = blockIdx.x * 256 + threadIdx.x;
    if (i >= N4K) return;
    float lb = prev[i], ub = prev[N4K + i];
    float a = fminf(fmaxf(alphas[i], 0.f), 1.f);
    if (lb > 0.f) a = 1.f;
    if (ub <= 0.f) a = 0.f;
    float slope = ub / (ub - lb + FLT_EPSILON);
    if (lb > 0.f) slope = 1.f;
    if (ub < 0.f) slope = 0.f;
    float bias = -lb * slope;
    if (lb > 0.f || ub < 0.f) bias = 0.f;
    long long P = NP1, half = (long long)N4K * NP1;
    out[(long long)i * P + i] = a;
    out[half + (long long)i * P + i] = slope;
    out[half + (long long)i * P + 4096] = bias;
}

extern "C" void kernel_launch(void* const* d_in, const int* in_sizes, int n_in,
                              void* d_out, int out_size, void* d_ws, size_t ws_size,
                              hipStream_t stream) {
    const float* lb0    = (const float*)d_in[0];
    const float* ub0    = (const float*)d_in[1];
    const float* W1lb   = (const float*)d_in[2];
    const float* W1ub   = (const float*)d_in[3];
    const float* W2lb   = (const float*)d_in[4];
    const float* W2ub   = (const float*)d_in[5];
    const float* alphas = (const float*)d_in[6];

    char* ws = (char*)d_ws;
    float* bias_part = (float*)ws;                               // 32768 B
    float* mb   = (float*)(ws + 32768);                          // 16384 B
    float* db   = (float*)(ws + 49152);                          // 16384 B
    float* prev = (float*)(ws + 32768);                          // reuses mb/db after they die
    unsigned short* Abf = (unsigned short*)(ws + 65536);         // 64 MiB
    unsigned short* Bmt = (unsigned short*)(ws + 65536 + 67108864);   // 32 MiB
    unsigned short* Bdt = (unsigned short*)(ws + 65536 + 100663296);  // 32 MiB
    size_t need = 65536ULL + 67108864ULL + 2ULL * 33554432ULL;
    if (ws_size < need) return;

    float* pp = (float*)d_out;   // 2 MiB scratch inside output, re-zeroed below

    (void)hipMemsetAsync(d_out, 0, (size_t)out_size * 4, stream);

    prep_mbdb<<<16, 256, 0, stream>>>(W1lb, W1ub, mb, db);
    prep_A2<<<8192, 256, 0, stream>>>(W2lb, W2ub, mb, db, Abf, bias_part);
    prep_B<<<dim3(64, 64), 256, 0, stream>>>(W1lb, W1ub, Bmt, Bdt);
    gemm_fused<<<512, 512, 0, stream>>>(Abf, Bmt, Bdt, lb0, ub0, pp);
    reduce_pp<<<32, 256, 0, stream>>>(pp, bias_part, prev);
    (void)hipMemsetAsync(d_out, 0, 64 * 8192 * 4, stream);   // clear pp scratch
    epilogue<<<16, 256, 0, stream>>>(prev, alphas, (float*)d_out);
}

// Round 6
// 2962.856 us; speedup vs baseline: 1.0079x; 1.0079x over previous
//
#include <hip/hip_runtime.h>
#include <float.h>

#define N4K 4096
#define NP1 4097

typedef __attribute__((ext_vector_type(4))) float f32x4;
typedef __attribute__((ext_vector_type(8))) short bf16x8;

__device__ __forceinline__ unsigned short f2bf(float x) {
    union { float f; unsigned int u; } v; v.f = x;
    unsigned int r = v.u + 0x7FFFu + ((v.u >> 16) & 1u);   // round-nearest-even
    return (unsigned short)(r >> 16);
}

__device__ __forceinline__ void gload_lds16(const void* g, void* l) {
    __builtin_amdgcn_global_load_lds(
        (const __attribute__((address_space(1))) unsigned int*)g,
        (__attribute__((address_space(3))) unsigned int*)l,
        16, 0, 0);
}

__device__ __forceinline__ void bar() {
    asm volatile("" ::: "memory");
    __builtin_amdgcn_s_barrier();
    asm volatile("" ::: "memory");
}

// ---- prep: W2 row -> bf16 cast + fused bias-matvec
__global__ __launch_bounds__(256) void prep_A2(const float* __restrict__ W2lb,
                                               const float* __restrict__ W2ub,
                                               const float* __restrict__ mb,
                                               const float* __restrict__ db,
                                               unsigned short* __restrict__ Abf,
                                               float* __restrict__ bias_part) {
    int b = blockIdx.x;                 // 0..8191
    int chain = b >> 12, i = b & 4095;
    const float* row = (chain ? W2ub : W2lb) + (long long)i * NP1;
    unsigned short* abf_row = Abf + ((long long)chain << 24) + (long long)i * N4K;
    float s = chain ? 1.f : -1.f;
    float part = 0.f;
#pragma unroll 4
    for (int p = 0; p < 16; ++p) {
        int k = threadIdx.x + p * 256;
        float wv = row[k];
        abf_row[k] = f2bf(wv);
        part += wv * mb[k] + s * db[k] * fabsf(wv);
    }
    __shared__ float red[4];
#pragma unroll
    for (int off = 32; off; off >>= 1) part += __shfl_down(part, off);
    if ((threadIdx.x & 63) == 0) red[threadIdx.x >> 6] = part;
    __syncthreads();
    if (threadIdx.x == 0)
        bias_part[b] = red[0] + red[1] + red[2] + red[3] + row[4096];
}

// ---- prep: build M^T, D^T bf16 [4096 j][4096 k] via LDS tile transpose
__global__ __launch_bounds__(256) void prep_B(const float* __restrict__ W1lb,
                                              const float* __restrict__ W1ub,
                                              unsigned short* __restrict__ Bmt,
                                              unsigned short* __restrict__ Bdt) {
    __shared__ unsigned short Lm[64 * 65];
    __shared__ unsigned short Ld[64 * 65];
    int j0 = blockIdx.x * 64, k0 = blockIdx.y * 64;
    int t = threadIdx.x;
    int jj = t & 63, kkb = t >> 6;
#pragma unroll 4
    for (int p = 0; p < 16; ++p) {
        int kk = kkb + p * 4;
        long long off = (long long)(k0 + kk) * NP1 + j0 + jj;
        float l = W1lb[off], u = W1ub[off];
        Lm[kk * 65 + jj] = f2bf(0.5f * (l + u));
        Ld[kk * 65 + jj] = f2bf(0.5f * (u - l));
    }
    __syncthreads();
#pragma unroll
    for (int p = 0; p < 2; ++p) {
        int jl = p * 32 + (t >> 3);
        int kl = (t & 7) * 8;
        bf16x8 vm, vd;
#pragma unroll
        for (int i = 0; i < 8; ++i) {
            vm[i] = (short)Lm[(kl + i) * 65 + jl];
            vd[i] = (short)Ld[(kl + i) * 65 + jl];
        }
        *(bf16x8*)&Bmt[(long long)(j0 + jl) * N4K + k0 + kl] = vm;
        *(bf16x8*)&Bdt[(long long)(j0 + jl) * N4K + k0 + kl] = vd;
    }
}

// ---- prep: bias column of W1 -> mb, db (fp32)
__global__ __launch_bounds__(256) void prep_mbdb(const float* __restrict__ W1lb,
                                                 const float* __restrict__ W1ub,
                                                 float* __restrict__ mb,
                                                 float* __restrict__ db) {
    int k = blockIdx.x * 256 + threadIdx.x;
    if (k < N4K) {
        float l = W1lb[(long long)k * NP1 + 4096];
        float u = W1ub[(long long)k * NP1 + 4096];
        mb[k] = 0.5f * (l + u);
        db[k] = 0.5f * (u - l);
    }
}

// ---- fused GEMM: 256x256 tile, BK=32, ring-3 LDS, 1 barrier/K-tile, counted vmcnt(6)
// __launch_bounds__(512, 1): 144 KiB LDS allows only 1 block/CU anyway; the ",2" in R5
// capped VGPRs at 128 and spilled acc[8][4] to scratch (7.9 GB scratch writes).
__global__ __launch_bounds__(512, 1) void gemm_fused(const unsigned short* __restrict__ Abf,
                                                     const unsigned short* __restrict__ Bmt,
                                                     const unsigned short* __restrict__ Bdt,
                                                     const float* __restrict__ lb0,
                                                     const float* __restrict__ ub0,
                                                     float* __restrict__ pp) {
    __shared__ unsigned short As[3][8192];    // 256 rows x 32 k
    __shared__ unsigned short Bms[3][8192];   // 256 cols x 32 k
    __shared__ unsigned short Bds[3][8192];

    int wg = blockIdx.x;
    int swz = (wg & 7) * 64 + (wg >> 3);      // XCD-aware bijective (512 % 8 == 0)
    int rt = swz & 31;                        // row tile: 16 lb + 16 ub
    int ct = swz >> 5;                        // col tile 0..15

    int chain = rt >> 4;
    const unsigned short* Aptr = Abf + ((long long)chain << 24) + (long long)(rt & 15) * 256 * N4K;
    const unsigned short* Bmp = Bmt + (long long)ct * 256 * N4K;
    const unsigned short* Bdp = Bdt + (long long)ct * 256 * N4K;

    int tid = threadIdx.x;
    int lane = tid & 63, w = tid >> 6;
    int wr = w >> 2, wc = w & 3;              // 2M x 4N waves, 128x64 per wave
    int la = lane & 15, kq = lane >> 4;
    int cA = (kq ^ ((la >> 1) & 3)) * 8;      // swizzled chunk offset (shorts)

    // staging source map (inverse-swizzled global chunk; linear LDS dest)
    int sr = tid >> 2;                               // 0..127
    int sce = ((tid & 3) ^ ((tid >> 3) & 3)) << 3;   // chunk*8 shorts
    const unsigned short* aB = Aptr + (long long)sr * N4K + sce;
    const unsigned short* mB = Bmp + (long long)sr * N4K + sce;
    const unsigned short* dB = Bdp + (long long)sr * N4K + sce;
    const long long R128 = 128LL * N4K;
    unsigned w512 = w * 512;                         // wave-uniform LDS base (shorts)

    f32x4 acc[8][4];
#pragma unroll
    for (int m = 0; m < 8; ++m)
#pragma unroll
        for (int n = 0; n < 4; ++n) acc[m][n] = (f32x4){0.f, 0.f, 0.f, 0.f};

#define STAGE(slot, koff)                                              \
    do {                                                               \
        gload_lds16(aB + (koff), &As[slot][w512]);                     \
        gload_lds16(aB + R128 + (koff), &As[slot][4096 + w512]);       \
        gload_lds16(mB + (koff), &Bms[slot][w512]);                    \
        gload_lds16(mB + R128 + (koff), &Bms[slot][4096 + w512]);      \
        gload_lds16(dB + (koff), &Bds[slot][w512]);                    \
        gload_lds16(dB + R128 + (koff), &Bds[slot][4096 + w512]);      \
    } while (0)

    // prologue: stage tiles 0,1 ; wait tile 0 ; barrier
    STAGE(0, 0);
    STAGE(1, 32);
    asm volatile("s_waitcnt vmcnt(6)" ::: "memory");
    bar();

#define FRAG(arr, s, rb) (*(const bf16x8*)&arr[s][((rb) + la) * 32 + cA])

    int cs = 0, st = 2;
#pragma unroll 1
    for (int t = 0; t < 128; ++t) {
        const bool pf = (t + 2 < 128);

        bf16x8 a[8], bm0[2], bd0[2], bm1[2], bd1[2];
#pragma unroll
        for (int m = 0; m < 8; ++m) a[m] = FRAG(As, cs, wr * 128 + m * 16);
#pragma unroll
        for (int n = 0; n < 2; ++n) {
            bm0[n] = FRAG(Bms, cs, wc * 64 + n * 16);
            bd0[n] = FRAG(Bds, cs, wc * 64 + n * 16);
        }
        if (pf) {
            long long koff = (long long)(t + 2) * 32;
            gload_lds16(aB + koff, &As[st][w512]);
            gload_lds16(aB + R128 + koff, &As[st][4096 + w512]);
            gload_lds16(mB + koff, &Bms[st][w512]);
        }
        __builtin_amdgcn_s_setprio(1);
#pragma unroll
        for (int m = 0; m < 8; ++m) {
            bf16x8 ax = chain ? (a[m] & (short)0x7FFF) : (a[m] | (short)0x8000);
#pragma unroll
            for (int n = 0; n < 2; ++n) {
                acc[m][n] = __builtin_amdgcn_mfma_f32_16x16x32_bf16(a[m], bm0[n], acc[m][n], 0, 0, 0);
                acc[m][n] = __builtin_amdgcn_mfma_f32_16x16x32_bf16(ax, bd0[n], acc[m][n], 0, 0, 0);
            }
        }
        __builtin_amdgcn_s_setprio(0);

#pragma unroll
        for (int n = 0; n < 2; ++n) {
            bm1[n] = FRAG(Bms, cs, wc * 64 + (n + 2) * 16);
            bd1[n] = FRAG(Bds, cs, wc * 64 + (n + 2) * 16);
        }
        if (pf) {
            long long koff = (long long)(t + 2) * 32;
            gload_lds16(mB + R128 + koff, &Bms[st][4096 + w512]);
            gload_lds16(dB + koff, &Bds[st][w512]);
            gload_lds16(dB + R128 + koff, &Bds[st][4096 + w512]);
        }
        __builtin_amdgcn_s_setprio(1);
#pragma unroll
        for (int m = 0; m < 8; ++m) {
            bf16x8 ax = chain ? (a[m] & (short)0x7FFF) : (a[m] | (short)0x8000);
#pragma unroll
            for (int n = 0; n < 2; ++n) {
                acc[m][n + 2] = __builtin_amdgcn_mfma_f32_16x16x32_bf16(a[m], bm1[n], acc[m][n + 2], 0, 0, 0);
                acc[m][n + 2] = __builtin_amdgcn_mfma_f32_16x16x32_bf16(ax, bd1[n], acc[m][n + 2], 0, 0, 0);
            }
        }
        __builtin_amdgcn_s_setprio(0);

        // boundary: require tile t+1 landed; leave tile t+2's 6 loads in flight
        if (pf) asm volatile("s_waitcnt vmcnt(6)" ::: "memory");
        else    asm volatile("s_waitcnt vmcnt(0)" ::: "memory");
        bar();

        cs = (cs == 2) ? 0 : cs + 1;
        st = (st == 2) ? 0 : st + 1;
    }
#undef FRAG
#undef STAGE

    // fused second backsub stage -> uncontended partial stores
    float s = chain ? 1.f : -1.f;
    float rowpart[8][4];
#pragma unroll
    for (int m = 0; m < 8; ++m)
#pragma unroll
        for (int r = 0; r < 4; ++r) rowpart[m][r] = 0.f;

    int jbase = ct * 256 + wc * 64;
#pragma unroll
    for (int n = 0; n < 4; ++n) {
        int j = jbase + n * 16 + la;
        float l0 = lb0[j], u0 = ub0[j];
        float mj = 0.5f * (l0 + u0);
        float sdj = s * 0.5f * (u0 - l0);
#pragma unroll
        for (int m = 0; m < 8; ++m)
#pragma unroll
            for (int r = 0; r < 4; ++r) {
                float v = acc[m][n][r];
                rowpart[m][r] += v * mj + sdj * fabsf(v);
            }
    }
    long long rowg = (long long)chain * N4K + (rt & 15) * 256 + wr * 128 + kq * 4;
    long long slice = (long long)(ct * 4 + wc) * 8192;
#pragma unroll
    for (int m = 0; m < 8; ++m)
#pragma unroll
        for (int r = 0; r < 4; ++r) {
            float v = rowpart[m][r];
            v += __shfl_xor(v, 1);
            v += __shfl_xor(v, 2);
            v += __shfl_xor(v, 4);
            v += __shfl_xor(v, 8);
            if (la == 0) pp[slice + rowg + m * 16 + r] = v;
        }
}

// ---- reduce 64 partial slices + bias -> prev[8192]
__global__ __launch_bounds__(256) void reduce_pp(const float* __restrict__ pp,
                                                 const float* __restrict__ bias_part,
                                                 float* __restrict__ prev) {
    int j = blockIdx.x * 256 + threadIdx.x;
    float s = bias_part[j];
#pragma unroll 8
    for (int c = 0; c < 64; ++c) s += pp[(long long)c * 8192 + j];
    prev[j] = s;
}

// ---- epilogue: PReLU relaxation, scatter diag + bias col
__global__ __launch_bounds__(256) void epilogue(const float* __restrict__ prev,
                                                const float* __restrict__ alphas,
                                                float* __restrict__ out) {
    int i = blockIdx.x * 256 + threadIdx.x;
    if (i >= N4K) return;
    float lb = prev[i], ub = prev[N4K + i];
    float a = fminf(fmaxf(alphas[i], 0.f), 1.f);
    if (lb > 0.f) a = 1.f;
    if (ub <= 0.f) a = 0.f;
    float slope = ub / (ub - lb + FLT_EPSILON);
    if (lb > 0.f) slope = 1.f;
    if (ub < 0.f) slope = 0.f;
    float bias = -lb * slope;
    if (lb > 0.f || ub < 0.f) bias = 0.f;
    long long P = NP1, half = (long long)N4K * NP1;
    out[(long long)i * P + i] = a;
    out[half + (long long)i * P + i] = slope;
    out[half + (long long)i * P + 4096] = bias;
}

extern "C" void kernel_launch(void* const* d_in, const int* in_sizes, int n_in,
                              void* d_out, int out_size, void* d_ws, size_t ws_size,
                              hipStream_t stream) {
    const float* lb0    = (const float*)d_in[0];
    const float* ub0    = (const float*)d_in[1];
    const float* W1lb   = (const float*)d_in[2];
    const float* W1ub   = (const float*)d_in[3];
    const float* W2lb   = (const float*)d_in[4];
    const float* W2ub   = (const float*)d_in[5];
    const float* alphas = (const float*)d_in[6];

    char* ws = (char*)d_ws;
    float* bias_part = (float*)ws;                               // 32768 B
    float* mb   = (float*)(ws + 32768);                          // 16384 B
    float* db   = (float*)(ws + 49152);                          // 16384 B
    float* prev = (float*)(ws + 32768);                          // reuses mb/db after they die
    unsigned short* Abf = (unsigned short*)(ws + 65536);         // 64 MiB
    unsigned short* Bmt = (unsigned short*)(ws + 65536 + 67108864);   // 32 MiB
    unsigned short* Bdt = (unsigned short*)(ws + 65536 + 100663296);  // 32 MiB
    size_t need = 65536ULL + 67108864ULL + 2ULL * 33554432ULL;
    if (ws_size < need) return;

    float* pp = (float*)d_out;   // 2 MiB scratch inside output, re-zeroed below

    (void)hipMemsetAsync(d_out, 0, (size_t)out_size * 4, stream);

    prep_mbdb<<<16, 256, 0, stream>>>(W1lb, W1ub, mb, db);
    prep_A2<<<8192, 256, 0, stream>>>(W2lb, W2ub, mb, db, Abf, bias_part);
    prep_B<<<dim3(64, 64), 256, 0, stream>>>(W1lb, W1ub, Bmt, Bdt);
    gemm_fused<<<512, 512, 0, stream>>>(Abf, Bmt, Bdt, lb0, ub0, pp);
    reduce_pp<<<32, 256, 0, stream>>>(pp, bias_part, prev);
    (void)hipMemsetAsync(d_out, 0, 64 * 8192 * 4, stream);   // clear pp scratch
    epilogue<<<16, 256, 0, stream>>>(prev, alphas, (float*)d_out);
}

// Round 7
// 716.960 us; speedup vs baseline: 4.1653x; 4.1325x over previous
//
#include <hip/hip_runtime.h>
#include <float.h>

#define N4K 4096
#define NP1 4097

typedef __attribute__((ext_vector_type(4))) float f32x4;
typedef __attribute__((ext_vector_type(8))) short bf16x8;

__device__ __forceinline__ unsigned short f2bf(float x) {
    union { float f; unsigned int u; } v; v.f = x;
    unsigned int r = v.u + 0x7FFFu + ((v.u >> 16) & 1u);   // round-nearest-even
    return (unsigned short)(r >> 16);
}

__device__ __forceinline__ void gload_lds16(const void* g, void* l) {
    __builtin_amdgcn_global_load_lds(
        (const __attribute__((address_space(1))) unsigned int*)g,
        (__attribute__((address_space(3))) unsigned int*)l,
        16, 0, 0);
}

__device__ __forceinline__ void bar() {
    asm volatile("" ::: "memory");
    __builtin_amdgcn_s_barrier();
    asm volatile("" ::: "memory");
}

// ---- prep: W2 row -> bf16 cast + fused bias-matvec
__global__ __launch_bounds__(256) void prep_A2(const float* __restrict__ W2lb,
                                               const float* __restrict__ W2ub,
                                               const float* __restrict__ mb,
                                               const float* __restrict__ db,
                                               unsigned short* __restrict__ Abf,
                                               float* __restrict__ bias_part) {
    int b = blockIdx.x;                 // 0..8191
    int chain = b >> 12, i = b & 4095;
    const float* row = (chain ? W2ub : W2lb) + (long long)i * NP1;
    unsigned short* abf_row = Abf + ((long long)chain << 24) + (long long)i * N4K;
    float s = chain ? 1.f : -1.f;
    float part = 0.f;
#pragma unroll 4
    for (int p = 0; p < 16; ++p) {
        int k = threadIdx.x + p * 256;
        float wv = row[k];
        abf_row[k] = f2bf(wv);
        part += wv * mb[k] + s * db[k] * fabsf(wv);
    }
    __shared__ float red[4];
#pragma unroll
    for (int off = 32; off; off >>= 1) part += __shfl_down(part, off);
    if ((threadIdx.x & 63) == 0) red[threadIdx.x >> 6] = part;
    __syncthreads();
    if (threadIdx.x == 0)
        bias_part[b] = red[0] + red[1] + red[2] + red[3] + row[4096];
}

// ---- prep: build M^T, D^T bf16 [4096 j][4096 k] via LDS tile transpose
__global__ __launch_bounds__(256) void prep_B(const float* __restrict__ W1lb,
                                              const float* __restrict__ W1ub,
                                              unsigned short* __restrict__ Bmt,
                                              unsigned short* __restrict__ Bdt) {
    __shared__ unsigned short Lm[64 * 65];
    __shared__ unsigned short Ld[64 * 65];
    int j0 = blockIdx.x * 64, k0 = blockIdx.y * 64;
    int t = threadIdx.x;
    int jj = t & 63, kkb = t >> 6;
#pragma unroll 4
    for (int p = 0; p < 16; ++p) {
        int kk = kkb + p * 4;
        long long off = (long long)(k0 + kk) * NP1 + j0 + jj;
        float l = W1lb[off], u = W1ub[off];
        Lm[kk * 65 + jj] = f2bf(0.5f * (l + u));
        Ld[kk * 65 + jj] = f2bf(0.5f * (u - l));
    }
    __syncthreads();
#pragma unroll
    for (int p = 0; p < 2; ++p) {
        int jl = p * 32 + (t >> 3);
        int kl = (t & 7) * 8;
        bf16x8 vm, vd;
#pragma unroll
        for (int i = 0; i < 8; ++i) {
            vm[i] = (short)Lm[(kl + i) * 65 + jl];
            vd[i] = (short)Ld[(kl + i) * 65 + jl];
        }
        *(bf16x8*)&Bmt[(long long)(j0 + jl) * N4K + k0 + kl] = vm;
        *(bf16x8*)&Bdt[(long long)(j0 + jl) * N4K + k0 + kl] = vd;
    }
}

// ---- prep: bias column of W1 -> mb, db (fp32)
__global__ __launch_bounds__(256) void prep_mbdb(const float* __restrict__ W1lb,
                                                 const float* __restrict__ W1ub,
                                                 float* __restrict__ mb,
                                                 float* __restrict__ db) {
    int k = blockIdx.x * 256 + threadIdx.x;
    if (k < N4K) {
        float l = W1lb[(long long)k * NP1 + 4096];
        float u = W1ub[(long long)k * NP1 + 4096];
        mb[k] = 0.5f * (l + u);
        db[k] = 0.5f * (u - l);
    }
}

// ---- fused GEMM: 256x128 tile, BK=32, ring-3 LDS (96 KiB), 1 barrier/K-tile,
// counted vmcnt(4). 8 waves of 64x64 -> acc[4][4] = 64 VGPRs: fits the 128-VGPR
// cap the allocator imposes on 512-thread kernels (R5/R6: acc[8][4] spilled 8 GB).
__global__ __launch_bounds__(512) void gemm_fused(const unsigned short* __restrict__ Abf,
                                                  const unsigned short* __restrict__ Bmt,
                                                  const unsigned short* __restrict__ Bdt,
                                                  const float* __restrict__ lb0,
                                                  const float* __restrict__ ub0,
                                                  float* __restrict__ pp) {
    __shared__ unsigned short As[3][8192];    // 256 rows x 32 k
    __shared__ unsigned short Bms[3][4096];   // 128 cols x 32 k
    __shared__ unsigned short Bds[3][4096];

    int wg = blockIdx.x;
    int swz = (wg & 7) * 128 + (wg >> 3);     // XCD-aware bijective (1024 % 8 == 0)
    int rt = swz & 31;                        // row tile: 16 lb + 16 ub
    int ct = swz >> 5;                        // col tile 0..31

    int chain = rt >> 4;
    const unsigned short* Aptr = Abf + ((long long)chain << 24) + (long long)(rt & 15) * 256 * N4K;
    const unsigned short* Bmp = Bmt + (long long)ct * 128 * N4K;
    const unsigned short* Bdp = Bdt + (long long)ct * 128 * N4K;

    int tid = threadIdx.x;
    int lane = tid & 63, w = tid >> 6;
    int wr = w >> 1, wc = w & 1;              // 4M x 2N waves, 64x64 per wave
    int la = lane & 15, kq = lane >> 4;
    int cA = (kq ^ ((la >> 1) & 3)) * 8;      // swizzled chunk offset (shorts)

    // staging source map (inverse-swizzled global chunk; linear LDS dest)
    int sr = tid >> 2;                               // 0..127
    int sce = ((tid & 3) ^ ((tid >> 3) & 3)) << 3;   // chunk*8 shorts
    const unsigned short* aB = Aptr + (long long)sr * N4K + sce;
    const unsigned short* mB = Bmp + (long long)sr * N4K + sce;
    const unsigned short* dB = Bdp + (long long)sr * N4K + sce;
    const long long R128 = 128LL * N4K;
    unsigned w512 = w * 512;                         // wave-uniform LDS base (shorts)

    f32x4 acc[4][4];
#pragma unroll
    for (int m = 0; m < 4; ++m)
#pragma unroll
        for (int n = 0; n < 4; ++n) acc[m][n] = (f32x4){0.f, 0.f, 0.f, 0.f};

#define STAGE(slot, koff)                                              \
    do {                                                               \
        gload_lds16(aB + (koff), &As[slot][w512]);                     \
        gload_lds16(aB + R128 + (koff), &As[slot][4096 + w512]);       \
        gload_lds16(mB + (koff), &Bms[slot][w512]);                    \
        gload_lds16(dB + (koff), &Bds[slot][w512]);                    \
    } while (0)

    // prologue: stage tiles 0,1 ; wait tile 0 ; barrier
    STAGE(0, 0);
    STAGE(1, 32);
    asm volatile("s_waitcnt vmcnt(4)" ::: "memory");
    bar();

#define FRAG(arr, s, rb) (*(const bf16x8*)&arr[s][((rb) + la) * 32 + cA])

    int cs = 0, st = 2;
#pragma unroll 1
    for (int t = 0; t < 128; ++t) {
        const bool pf = (t + 2 < 128);
        const long long koff = (long long)(t + 2) * 32;

        bf16x8 a[4], b0[2], b1[2];

        // half 1: A frags + {Bm,Bd} n=0,1 ; stage next A ; 16 MFMA
#pragma unroll
        for (int m = 0; m < 4; ++m) a[m] = FRAG(As, cs, wr * 64 + m * 16);
#pragma unroll
        for (int n = 0; n < 2; ++n) {
            b0[n] = FRAG(Bms, cs, wc * 64 + n * 16);
            b1[n] = FRAG(Bds, cs, wc * 64 + n * 16);
        }
        if (pf) {
            gload_lds16(aB + koff, &As[st][w512]);
            gload_lds16(aB + R128 + koff, &As[st][4096 + w512]);
        }
        __builtin_amdgcn_s_setprio(1);
#pragma unroll
        for (int m = 0; m < 4; ++m) {
            bf16x8 ax = chain ? (a[m] & (short)0x7FFF) : (a[m] | (short)0x8000);
#pragma unroll
            for (int n = 0; n < 2; ++n) {
                acc[m][n] = __builtin_amdgcn_mfma_f32_16x16x32_bf16(a[m], b0[n], acc[m][n], 0, 0, 0);
                acc[m][n] = __builtin_amdgcn_mfma_f32_16x16x32_bf16(ax, b1[n], acc[m][n], 0, 0, 0);
            }
        }
        __builtin_amdgcn_s_setprio(0);

        // half 2: {Bm,Bd} n=2,3 ; stage next Bm,Bd ; 16 MFMA
#pragma unroll
        for (int n = 0; n < 2; ++n) {
            b0[n] = FRAG(Bms, cs, wc * 64 + (n + 2) * 16);
            b1[n] = FRAG(Bds, cs, wc * 64 + (n + 2) * 16);
        }
        if (pf) {
            gload_lds16(mB + koff, &Bms[st][w512]);
            gload_lds16(dB + koff, &Bds[st][w512]);
        }
        __builtin_amdgcn_s_setprio(1);
#pragma unroll
        for (int m = 0; m < 4; ++m) {
            bf16x8 ax = chain ? (a[m] & (short)0x7FFF) : (a[m] | (short)0x8000);
#pragma unroll
            for (int n = 0; n < 2; ++n) {
                acc[m][n + 2] = __builtin_amdgcn_mfma_f32_16x16x32_bf16(a[m], b0[n], acc[m][n + 2], 0, 0, 0);
                acc[m][n + 2] = __builtin_amdgcn_mfma_f32_16x16x32_bf16(ax, b1[n], acc[m][n + 2], 0, 0, 0);
            }
        }
        __builtin_amdgcn_s_setprio(0);

        // boundary: require tile t+1 landed; leave tile t+2's 4 loads in flight
        if (pf) asm volatile("s_waitcnt vmcnt(4)" ::: "memory");
        else    asm volatile("s_waitcnt vmcnt(0)" ::: "memory");
        bar();

        cs = (cs == 2) ? 0 : cs + 1;
        st = (st == 2) ? 0 : st + 1;
    }
#undef FRAG
#undef STAGE

    // fused second backsub stage -> uncontended partial stores
    float s = chain ? 1.f : -1.f;
    float rowpart[4][4];
#pragma unroll
    for (int m = 0; m < 4; ++m)
#pragma unroll
        for (int r = 0; r < 4; ++r) rowpart[m][r] = 0.f;

    int jbase = ct * 128 + wc * 64;
#pragma unroll
    for (int n = 0; n < 4; ++n) {
        int j = jbase + n * 16 + la;
        float l0 = lb0[j], u0 = ub0[j];
        float mj = 0.5f * (l0 + u0);
        float sdj = s * 0.5f * (u0 - l0);
#pragma unroll
        for (int m = 0; m < 4; ++m)
#pragma unroll
            for (int r = 0; r < 4; ++r) {
                float v = acc[m][n][r];
                rowpart[m][r] += v * mj + sdj * fabsf(v);
            }
    }
    long long rowg = (long long)chain * N4K + (rt & 15) * 256 + wr * 64 + kq * 4;
    long long slice = (long long)(ct * 2 + wc) * 8192;
#pragma unroll
    for (int m = 0; m < 4; ++m)
#pragma unroll
        for (int r = 0; r < 4; ++r) {
            float v = rowpart[m][r];
            v += __shfl_xor(v, 1);
            v += __shfl_xor(v, 2);
            v += __shfl_xor(v, 4);
            v += __shfl_xor(v, 8);
            if (la == 0) pp[slice + rowg + m * 16 + r] = v;
        }
}

// ---- reduce 64 partial slices + bias -> prev[8192]
__global__ __launch_bounds__(256) void reduce_pp(const float* __restrict__ pp,
                                                 const float* __restrict__ bias_part,
                                                 float* __restrict__ prev) {
    int j = blockIdx.x * 256 + threadIdx.x;
    float s = bias_part[j];
#pragma unroll 8
    for (int c = 0; c < 64; ++c) s += pp[(long long)c * 8192 + j];
    prev[j] = s;
}

// ---- epilogue: PReLU relaxation, scatter diag + bias col
__global__ __launch_bounds__(256) void epilogue(const float* __restrict__ prev,
                                                const float* __restrict__ alphas,
                                                float* __restrict__ out) {
    int i = blockIdx.x * 256 + threadIdx.x;
    if (i >= N4K) return;
    float lb = prev[i], ub = prev[N4K + i];
    float a = fminf(fmaxf(alphas[i], 0.f), 1.f);
    if (lb > 0.f) a = 1.f;
    if (ub <= 0.f) a = 0.f;
    float slope = ub / (ub - lb + FLT_EPSILON);
    if (lb > 0.f) slope = 1.f;
    if (ub < 0.f) slope = 0.f;
    float bias = -lb * slope;
    if (lb > 0.f || ub < 0.f) bias = 0.f;
    long long P = NP1, half = (long long)N4K * NP1;
    out[(long long)i * P + i] = a;
    out[half + (long long)i * P + i] = slope;
    out[half + (long long)i * P + 4096] = bias;
}

extern "C" void kernel_launch(void* const* d_in, const int* in_sizes, int n_in,
                              void* d_out, int out_size, void* d_ws, size_t ws_size,
                              hipStream_t stream) {
    const float* lb0    = (const float*)d_in[0];
    const float* ub0    = (const float*)d_in[1];
    const float* W1lb   = (const float*)d_in[2];
    const float* W1ub   = (const float*)d_in[3];
    const float* W2lb   = (const float*)d_in[4];
    const float* W2ub   = (const float*)d_in[5];
    const float* alphas = (const float*)d_in[6];

    char* ws = (char*)d_ws;
    float* bias_part = (float*)ws;                               // 32768 B
    float* mb   = (float*)(ws + 32768);                          // 16384 B
    float* db   = (float*)(ws + 49152);                          // 16384 B
    float* prev = (float*)(ws + 32768);                          // reuses mb/db after they die
    unsigned short* Abf = (unsigned short*)(ws + 65536);         // 64 MiB
    unsigned short* Bmt = (unsigned short*)(ws + 65536 + 67108864);   // 32 MiB
    unsigned short* Bdt = (unsigned short*)(ws + 65536 + 100663296);  // 32 MiB
    size_t need = 65536ULL + 67108864ULL + 2ULL * 33554432ULL;
    if (ws_size < need) return;

    float* pp = (float*)d_out;   // 2 MiB scratch inside output, re-zeroed below

    (void)hipMemsetAsync(d_out, 0, (size_t)out_size * 4, stream);

    prep_mbdb<<<16, 256, 0, stream>>>(W1lb, W1ub, mb, db);
    prep_A2<<<8192, 256, 0, stream>>>(W2lb, W2ub, mb, db, Abf, bias_part);
    prep_B<<<dim3(64, 64), 256, 0, stream>>>(W1lb, W1ub, Bmt, Bdt);
    gemm_fused<<<1024, 512, 0, stream>>>(Abf, Bmt, Bdt, lb0, ub0, pp);
    reduce_pp<<<32, 256, 0, stream>>>(pp, bias_part, prev);
    (void)hipMemsetAsync(d_out, 0, 64 * 8192 * 4, stream);   // clear pp scratch
    epilogue<<<16, 256, 0, stream>>>(prev, alphas, (float*)d_out);
}